// Round 1
// baseline (371.159 us; speedup 1.0000x reference)
//
#include <hip/hip_runtime.h>
#include <hip/hip_bf16.h>
#include <stdint.h>

typedef __attribute__((ext_vector_type(8))) short bf16x8;
typedef __attribute__((ext_vector_type(4))) float f32x4;
typedef __attribute__((ext_vector_type(8))) unsigned short ushort8;

__device__ __forceinline__ float bf2f(unsigned short u) {
  union { unsigned int i; float f; } x; x.i = ((unsigned int)u) << 16; return x.f;
}
__device__ __forceinline__ unsigned short f2bf(float f) {
  union { __hip_bfloat16 h; unsigned short u; } x; x.h = __float2bfloat16(f); return x.u;
}

__device__ __forceinline__ void gload_lds16(const void* g, void* l) {
  __builtin_amdgcn_global_load_lds((__attribute__((address_space(1))) const void*)g,
                                   (__attribute__((address_space(3))) void*)l, 16, 0, 0);
}

// ---------------- f32 -> bf16 convert, 8 elems/thread ----------------
__global__ __launch_bounds__(256) void cvt_bf16_kernel(const float* __restrict__ in,
                                                       unsigned short* __restrict__ out,
                                                       int n8) {
  int i = blockIdx.x * 256 + threadIdx.x;
  if (i >= n8) return;
  const float4* p = (const float4*)(in + (size_t)i * 8);
  float4 a = p[0], b = p[1];
  ushort8 o;
  o[0] = f2bf(a.x); o[1] = f2bf(a.y); o[2] = f2bf(a.z); o[3] = f2bf(a.w);
  o[4] = f2bf(b.x); o[5] = f2bf(b.y); o[6] = f2bf(b.z); o[7] = f2bf(b.w);
  *(ushort8*)(out + (size_t)i * 8) = o;
}

// ---------------- projection GEMM: C[M,N] = A[M,K] * B[N,K]^T + bias ----------------
// A,B,C bf16; bias f32. 128x128 tile, BK=32, 4 waves, 16x16x32 MFMA.
__global__ __launch_bounds__(256) void gemm_bias_kernel(
    const unsigned short* __restrict__ A,
    const unsigned short* __restrict__ B,
    const float* __restrict__ bias,
    unsigned short* __restrict__ C,
    int M, int N, int K) {
  __shared__ unsigned short As[128][32];
  __shared__ unsigned short Bs[128][32];
  const int tid = threadIdx.x;
  const int wid = tid >> 6;
  const int lane = tid & 63;
  const int bn = blockIdx.x, bm = blockIdx.y;
  const int wrow = (wid >> 1) * 64, wcol = (wid & 1) * 64;
  const int lrow = lane >> 2, lcol = lane & 3;
  const int fr = lane & 15, fk = (lane >> 4) * 8;

  f32x4 acc[4][4];
#pragma unroll
  for (int m = 0; m < 4; ++m)
#pragma unroll
    for (int n = 0; n < 4; ++n) acc[m][n] = (f32x4){0.f, 0.f, 0.f, 0.f};

  const size_t abase = (size_t)(bm * 128) * K;
  const size_t bbase = (size_t)(bn * 128) * K;

  for (int kt = 0; kt < K; kt += 32) {
#pragma unroll
    for (int it = 0; it < 2; ++it) {
      const int chunk = wid * 2 + it;
      gload_lds16(A + abase + (size_t)(chunk * 16 + lrow) * K + kt + lcol * 8,
                  &As[chunk * 16][0]);
      gload_lds16(B + bbase + (size_t)(chunk * 16 + lrow) * K + kt + lcol * 8,
                  &Bs[chunk * 16][0]);
    }
    __syncthreads();
    bf16x8 af[4], bfr[4];
#pragma unroll
    for (int m = 0; m < 4; ++m) af[m] = *(const bf16x8*)&As[wrow + m * 16 + fr][fk];
#pragma unroll
    for (int n = 0; n < 4; ++n) bfr[n] = *(const bf16x8*)&Bs[wcol + n * 16 + fr][fk];
#pragma unroll
    for (int m = 0; m < 4; ++m)
#pragma unroll
      for (int n = 0; n < 4; ++n)
        acc[m][n] = __builtin_amdgcn_mfma_f32_16x16x32_bf16(af[m], bfr[n], acc[m][n], 0, 0, 0);
    __syncthreads();
  }

  // epilogue: bias add, bf16 store
#pragma unroll
  for (int n = 0; n < 4; ++n) {
    int col = bn * 128 + wcol + n * 16 + fr;
    float bsv = bias[col];
#pragma unroll
    for (int m = 0; m < 4; ++m) {
#pragma unroll
      for (int j = 0; j < 4; ++j) {
        int row = bm * 128 + wrow + m * 16 + (lane >> 4) * 4 + j;
        C[(size_t)row * N + col] = f2bf(acc[m][n][j] + bsv);
      }
    }
  }
}

// ---------------- in-place L2 normalize of each contiguous 64-elem head block ----------------
__global__ __launch_bounds__(256) void norm64_kernel(unsigned short* __restrict__ x, int ngrp) {
  int t = blockIdx.x * 256 + threadIdx.x;
  int g = t >> 3;
  if (g >= ngrp) return;
  int sub = t & 7;
  unsigned short* p = x + (size_t)g * 64 + sub * 8;
  ushort8 v = *(const ushort8*)p;
  float f[8];
  float s = 0.f;
#pragma unroll
  for (int j = 0; j < 8; ++j) { f[j] = bf2f(v[j]); s += f[j] * f[j]; }
  s += __shfl_xor(s, 1);
  s += __shfl_xor(s, 2);
  s += __shfl_xor(s, 4);
  float inv = 1.f / fmaxf(sqrtf(s), 1e-12f);
  ushort8 o;
#pragma unroll
  for (int j = 0; j < 8; ++j) o[j] = f2bf(f[j] * inv);
  *(ushort8*)p = o;
}

// ---------------- kv[b,h,i,j] += sum_s kh[b,s,h*64+i] * vh[b,s,h*64+j] ----------------
// grid (chunk=16, h=16, b=4), block 256. f32 accumulation, atomics across chunks.
__global__ __launch_bounds__(256) void kv_kernel(const unsigned short* __restrict__ kh,
                                                 const unsigned short* __restrict__ vh,
                                                 float* __restrict__ kv) {
  const int chunk = blockIdx.x, h = blockIdx.y, b = blockIdx.z;
  __shared__ float ks_[32][64];
  __shared__ float vs_[32][64];
  const int tid = threadIdx.x;
  const int ti = tid >> 4, tj = tid & 15;
  const int r = tid >> 3, sub = tid & 7;
  float acc[4][4] = {{0.f}};
  const size_t rowbase = (size_t)b * 4096;

  for (int st = 0; st < 256; st += 32) {
    int s = chunk * 256 + st + r;
    ushort8 kvv = *(const ushort8*)(kh + (rowbase + s) * 1024 + h * 64 + sub * 8);
    ushort8 vvv = *(const ushort8*)(vh + (rowbase + s) * 1024 + h * 64 + sub * 8);
    __syncthreads();
#pragma unroll
    for (int u = 0; u < 8; ++u) {
      ks_[r][sub * 8 + u] = bf2f(kvv[u]);
      vs_[r][sub * 8 + u] = bf2f(vvv[u]);
    }
    __syncthreads();
#pragma unroll 4
    for (int s2 = 0; s2 < 32; ++s2) {
      float4 kf = *(const float4*)&ks_[s2][ti * 4];
      float4 vf = *(const float4*)&vs_[s2][tj * 4];
      acc[0][0] += kf.x * vf.x; acc[0][1] += kf.x * vf.y; acc[0][2] += kf.x * vf.z; acc[0][3] += kf.x * vf.w;
      acc[1][0] += kf.y * vf.x; acc[1][1] += kf.y * vf.y; acc[1][2] += kf.y * vf.z; acc[1][3] += kf.y * vf.w;
      acc[2][0] += kf.z * vf.x; acc[2][1] += kf.z * vf.y; acc[2][2] += kf.z * vf.z; acc[2][3] += kf.z * vf.w;
      acc[3][0] += kf.w * vf.x; acc[3][1] += kf.w * vf.y; acc[3][2] += kf.w * vf.z; acc[3][3] += kf.w * vf.w;
    }
  }
  float* dst = kv + ((size_t)(b * 16 + h)) * 4096;
#pragma unroll
  for (int a = 0; a < 4; ++a)
#pragma unroll
    for (int c = 0; c < 4; ++c)
      atomicAdd(&dst[(ti * 4 + a) * 64 + tj * 4 + c], acc[a][c]);
}

// ---------------- out[b,l,h*64+j] = sum_i qp[b,l,h*64+i] * kv[b,h,i,j] ----------------
// grid (h=16, rowtile=128 of 128 rows), block 256 (4 waves, 32 rows x 64 cols each).
__global__ __launch_bounds__(256) void final_kernel(const unsigned short* __restrict__ qp,
                                                    const float* __restrict__ kv,
                                                    float* __restrict__ out) {
  const int h = blockIdx.x;
  const int rt = blockIdx.y;
  const int b = rt >> 5;
  // fragment-major bf16 kv: [kchunk=i>>3][j][i&7]
  __shared__ unsigned short kvb[8 * 64 * 8];
  const int tid = threadIdx.x;
  const int wid = tid >> 6;
  const int lane = tid & 63;

  {
    const float* src = kv + ((size_t)(b * 16 + h)) * 4096;
    for (int e = tid; e < 4096; e += 256) {
      int i = e >> 6, j = e & 63;
      kvb[((i >> 3) * 64 + j) * 8 + (i & 7)] = f2bf(src[e]);
    }
  }
  __syncthreads();

  const int fr = lane & 15, fkg = lane >> 4;
  const int row0 = rt * 128 + wid * 32;
  f32x4 acc[2][4];
#pragma unroll
  for (int m = 0; m < 2; ++m)
#pragma unroll
    for (int n = 0; n < 4; ++n) acc[m][n] = (f32x4){0.f, 0.f, 0.f, 0.f};

#pragma unroll
  for (int ks = 0; ks < 2; ++ks) {
    bf16x8 bfr[4];
#pragma unroll
    for (int n = 0; n < 4; ++n)
      bfr[n] = *(const bf16x8*)&kvb[(((ks * 4 + fkg) * 64) + n * 16 + fr) * 8];
#pragma unroll
    for (int m = 0; m < 2; ++m) {
      const unsigned short* ga =
          qp + (size_t)(row0 + m * 16 + fr) * 1024 + h * 64 + ks * 32 + fkg * 8;
      bf16x8 afv = *(const bf16x8*)ga;
#pragma unroll
      for (int n = 0; n < 4; ++n)
        acc[m][n] = __builtin_amdgcn_mfma_f32_16x16x32_bf16(afv, bfr[n], acc[m][n], 0, 0, 0);
    }
  }

#pragma unroll
  for (int m = 0; m < 2; ++m)
#pragma unroll
    for (int n = 0; n < 4; ++n) {
      int col = h * 64 + n * 16 + fr;
#pragma unroll
      for (int j = 0; j < 4; ++j) {
        int row = row0 + m * 16 + (lane >> 4) * 4 + j;
        out[(size_t)row * 1024 + col] = acc[m][n][j];
      }
    }
}

extern "C" void kernel_launch(void* const* d_in, const int* in_sizes, int n_in,
                              void* d_out, int out_size, void* d_ws, size_t ws_size,
                              hipStream_t stream) {
  const float* q = (const float*)d_in[0];
  const float* k = (const float*)d_in[1];
  const float* v = (const float*)d_in[2];
  const float* Wq = (const float*)d_in[3];
  const float* bq = (const float*)d_in[4];
  const float* Wk = (const float*)d_in[5];
  const float* bk = (const float*)d_in[6];
  const float* Wv = (const float*)d_in[7];
  const float* bv = (const float*)d_in[8];
  float* out = (float*)d_out;

  const int M = 16384;   // B*L = B*S
  const int D = 1024;
  const size_t NE = (size_t)M * D;        // 16,777,216 elements
  const size_t SLOT = NE * 2;             // bf16 bytes = 33,554,432

  char* ws = (char*)d_ws;
  unsigned short* S0 = (unsigned short*)(ws + 0 * SLOT);
  unsigned short* S1 = (unsigned short*)(ws + 1 * SLOT);
  unsigned short* S2 = (unsigned short*)(ws + 2 * SLOT);
  unsigned short* S3 = (unsigned short*)(ws + 3 * SLOT);
  unsigned short* Wqb = (unsigned short*)(ws + 4 * SLOT);
  unsigned short* Wkb = (unsigned short*)(ws + 4 * SLOT + 2097152);
  unsigned short* Wvb = (unsigned short*)(ws + 4 * SLOT + 2 * 2097152);
  float* kvb = (float*)(ws + 4 * SLOT + 3 * 2097152);   // 64*64*64 f32 = 1 MB

  // 1) convert inputs + weights to bf16
  cvt_bf16_kernel<<<8192, 256, 0, stream>>>(q, S0, (int)(NE / 8));
  cvt_bf16_kernel<<<8192, 256, 0, stream>>>(k, S1, (int)(NE / 8));
  cvt_bf16_kernel<<<8192, 256, 0, stream>>>(v, S2, (int)(NE / 8));
  cvt_bf16_kernel<<<512, 256, 0, stream>>>(Wq, Wqb, 131072);
  cvt_bf16_kernel<<<512, 256, 0, stream>>>(Wk, Wkb, 131072);
  cvt_bf16_kernel<<<512, 256, 0, stream>>>(Wv, Wvb, 131072);

  // 2) projections (x @ W^T + b)
  dim3 ggrid(8, 128);
  gemm_bias_kernel<<<ggrid, 256, 0, stream>>>(S0, Wqb, bq, S3, M, D, D);  // qp -> S3
  gemm_bias_kernel<<<ggrid, 256, 0, stream>>>(S1, Wkb, bk, S0, M, D, D);  // kp -> S0
  gemm_bias_kernel<<<ggrid, 256, 0, stream>>>(S2, Wvb, bv, S1, M, D, D);  // vp -> S1

  // 3) per-head L2 normalize (in place)
  norm64_kernel<<<8192, 256, 0, stream>>>(S0, (int)(NE / 64));  // kh
  norm64_kernel<<<8192, 256, 0, stream>>>(S1, (int)(NE / 64));  // vh

  // 4) kv = kh^T vh per (b,h)
  hipMemsetAsync(kvb, 0, 64 * 64 * 64 * sizeof(float), stream);
  kv_kernel<<<dim3(16, 16, 4), 256, 0, stream>>>(S0, S1, kvb);

  // 5) out = qp @ kv (per head), merge heads, f32 out
  final_kernel<<<dim3(16, 128), 256, 0, stream>>>(S3, kvb, out);
}

// Round 2
// 285.773 us; speedup vs baseline: 1.2988x; 1.2988x over previous
//
#include <hip/hip_runtime.h>
#include <hip/hip_bf16.h>
#include <stdint.h>

typedef __attribute__((ext_vector_type(8))) short bf16x8;
typedef __attribute__((ext_vector_type(4))) float f32x4;
typedef __attribute__((ext_vector_type(8))) unsigned short ushort8;

__device__ __forceinline__ float bf2f(unsigned short u) {
  union { unsigned int i; float f; } x; x.i = ((unsigned int)u) << 16; return x.f;
}
__device__ __forceinline__ unsigned short f2bf(float f) {
  union { __hip_bfloat16 h; unsigned short u; } x; x.h = __float2bfloat16(f); return x.u;
}

__device__ __forceinline__ void gload_lds16(const void* g, void* l) {
  __builtin_amdgcn_global_load_lds((__attribute__((address_space(1))) const void*)g,
                                   (__attribute__((address_space(3))) void*)l, 16, 0, 0);
}

// ---------------- f32 -> bf16 converts ----------------
__global__ __launch_bounds__(256) void cvt_kernel(const float* __restrict__ in,
                                                  unsigned short* __restrict__ out,
                                                  int n8) {
  int i = blockIdx.x * 256 + threadIdx.x;
  if (i >= n8) return;
  const float4* p = (const float4*)(in + (size_t)i * 8);
  float4 a = p[0], b = p[1];
  ushort8 o;
  o[0] = f2bf(a.x); o[1] = f2bf(a.y); o[2] = f2bf(a.z); o[3] = f2bf(a.w);
  o[4] = f2bf(b.x); o[5] = f2bf(b.y); o[6] = f2bf(b.z); o[7] = f2bf(b.w);
  *(ushort8*)(out + (size_t)i * 8) = o;
}

__global__ __launch_bounds__(256) void cvt2_kernel(const float* __restrict__ a,
                                                   const float* __restrict__ b,
                                                   unsigned short* __restrict__ oa,
                                                   unsigned short* __restrict__ ob,
                                                   int n8) {
  const float* in = blockIdx.y ? b : a;
  unsigned short* out = blockIdx.y ? ob : oa;
  int i = blockIdx.x * 256 + threadIdx.x;
  if (i >= n8) return;
  const float4* p = (const float4*)(in + (size_t)i * 8);
  float4 x = p[0], y = p[1];
  ushort8 o;
  o[0] = f2bf(x.x); o[1] = f2bf(x.y); o[2] = f2bf(x.z); o[3] = f2bf(x.w);
  o[4] = f2bf(y.x); o[5] = f2bf(y.y); o[6] = f2bf(y.z); o[7] = f2bf(y.w);
  *(ushort8*)(out + (size_t)i * 8) = o;
}

__global__ __launch_bounds__(256) void cvt3w_kernel(const float* __restrict__ a,
                                                    const float* __restrict__ b,
                                                    const float* __restrict__ c,
                                                    unsigned short* __restrict__ oa,
                                                    unsigned short* __restrict__ ob,
                                                    unsigned short* __restrict__ oc,
                                                    int n8) {
  const float* in = blockIdx.y == 0 ? a : blockIdx.y == 1 ? b : c;
  unsigned short* out = blockIdx.y == 0 ? oa : blockIdx.y == 1 ? ob : oc;
  int i = blockIdx.x * 256 + threadIdx.x;
  if (i >= n8) return;
  const float4* p = (const float4*)(in + (size_t)i * 8);
  float4 x = p[0], y = p[1];
  ushort8 o;
  o[0] = f2bf(x.x); o[1] = f2bf(x.y); o[2] = f2bf(x.z); o[3] = f2bf(x.w);
  o[4] = f2bf(y.x); o[5] = f2bf(y.y); o[6] = f2bf(y.z); o[7] = f2bf(y.w);
  *(ushort8*)(out + (size_t)i * 8) = o;
}

// ---------------- shared GEMM tile body: C = A[M,K=1024] * B[N=1024,K]^T + bias ----------------
// 128x128 tile, BK=32, 4 waves, 16x16x32 MFMA. F32OUT selects f32 vs bf16 C.
template <bool F32OUT>
__device__ __forceinline__ void gemm_tile_body(
    const unsigned short* __restrict__ A,
    const unsigned short* __restrict__ B,
    const float* __restrict__ bias,
    void* __restrict__ C,
    int bm, int bn,
    unsigned short (*As)[32], unsigned short (*Bs)[32]) {
  const int tid = threadIdx.x;
  const int wid = tid >> 6;
  const int lane = tid & 63;
  const int wrow = (wid >> 1) * 64, wcol = (wid & 1) * 64;
  const int lrow = lane >> 2, lcol = lane & 3;
  const int fr = lane & 15, fk = (lane >> 4) * 8;

  f32x4 acc[4][4];
#pragma unroll
  for (int m = 0; m < 4; ++m)
#pragma unroll
    for (int n = 0; n < 4; ++n) acc[m][n] = (f32x4){0.f, 0.f, 0.f, 0.f};

  const size_t abase = (size_t)(bm * 128) * 1024;
  const size_t bbase = (size_t)(bn * 128) * 1024;

  for (int kt = 0; kt < 1024; kt += 32) {
#pragma unroll
    for (int it = 0; it < 2; ++it) {
      const int chunk = wid * 2 + it;
      gload_lds16(A + abase + (size_t)(chunk * 16 + lrow) * 1024 + kt + lcol * 8,
                  &As[chunk * 16][0]);
      gload_lds16(B + bbase + (size_t)(chunk * 16 + lrow) * 1024 + kt + lcol * 8,
                  &Bs[chunk * 16][0]);
    }
    __syncthreads();
    bf16x8 af[4], bfr[4];
#pragma unroll
    for (int m = 0; m < 4; ++m) af[m] = *(const bf16x8*)&As[wrow + m * 16 + fr][fk];
#pragma unroll
    for (int n = 0; n < 4; ++n) bfr[n] = *(const bf16x8*)&Bs[wcol + n * 16 + fr][fk];
#pragma unroll
    for (int m = 0; m < 4; ++m)
#pragma unroll
      for (int n = 0; n < 4; ++n)
        acc[m][n] = __builtin_amdgcn_mfma_f32_16x16x32_bf16(af[m], bfr[n], acc[m][n], 0, 0, 0);
    __syncthreads();
  }

#pragma unroll
  for (int n = 0; n < 4; ++n) {
    int col = bn * 128 + wcol + n * 16 + fr;
    float bsv = bias[col];
#pragma unroll
    for (int m = 0; m < 4; ++m) {
#pragma unroll
      for (int j = 0; j < 4; ++j) {
        int row = bm * 128 + wrow + m * 16 + (lane >> 4) * 4 + j;
        if (F32OUT)
          ((float*)C)[(size_t)row * 1024 + col] = acc[m][n][j] + bsv;
        else
          ((unsigned short*)C)[(size_t)row * 1024 + col] = f2bf(acc[m][n][j] + bsv);
      }
    }
  }
}

// ---------------- batched projection GEMM (z=2: kp and vp), XCD-swizzled ----------------
__global__ __launch_bounds__(256) void proj_gemm_kernel(
    const unsigned short* __restrict__ A0, const unsigned short* __restrict__ A1,
    const unsigned short* __restrict__ B0, const unsigned short* __restrict__ B1,
    const float* __restrict__ bias0, const float* __restrict__ bias1,
    unsigned short* __restrict__ C0, unsigned short* __restrict__ C1) {
  __shared__ unsigned short As[128][32];
  __shared__ unsigned short Bs[128][32];
  // grid (8, 128, 2) -> nwg = 2048, divisible by 8 XCDs
  int flat = (blockIdx.z * 128 + blockIdx.y) * 8 + blockIdx.x;
  int swz = (flat & 7) * 256 + (flat >> 3);
  int zz = swz >> 10;
  int rem = swz & 1023;
  int bm = rem >> 3, bn = rem & 7;
  const unsigned short* A = zz ? A1 : A0;
  const unsigned short* B = zz ? B1 : B0;
  const float* bias = zz ? bias1 : bias0;
  unsigned short* C = zz ? C1 : C0;
  gemm_tile_body<false>(A, B, bias, C, bm, bn, As, Bs);
}

// ---------------- final GEMM: out = q_bf @ Beff_b^T + beff_b (f32 out), XCD-swizzled ----------------
__global__ __launch_bounds__(256) void final_gemm_kernel(
    const unsigned short* __restrict__ A,     // q_bf [16384][1024]
    const unsigned short* __restrict__ Beff,  // [4][1024][1024] bf16
    const float* __restrict__ beff,           // [4][1024]
    float* __restrict__ out) {
  __shared__ unsigned short As[128][32];
  __shared__ unsigned short Bs[128][32];
  int flat = blockIdx.y * 8 + blockIdx.x;  // nwg = 1024
  int swz = (flat & 7) * 128 + (flat >> 3);
  int bm = swz >> 3, bn = swz & 7;
  int b = bm >> 5;  // 128 row-blocks / 4 batches
  gemm_tile_body<true>(A, Beff + (size_t)b * 1048576, beff + b * 1024, out, bm, bn, As, Bs);
}

// ---------------- kv[b,h,i,j] += sum_s norm(kp)[..i] * norm(vp)[..j], norm fused ----------------
__global__ __launch_bounds__(256) void kv_kernel(const unsigned short* __restrict__ kp,
                                                 const unsigned short* __restrict__ vp,
                                                 float* __restrict__ kv) {
  const int chunk = blockIdx.x, h = blockIdx.y, b = blockIdx.z;
  __shared__ float ks_[32][64];
  __shared__ float vs_[32][64];
  const int tid = threadIdx.x;
  const int ti = tid >> 4, tj = tid & 15;
  const int r = tid >> 3, sub = tid & 7;
  float acc[4][4] = {{0.f}};
  const size_t rowbase = (size_t)b * 4096;

  for (int st = 0; st < 256; st += 32) {
    int s = chunk * 256 + st + r;
    ushort8 kvv = *(const ushort8*)(kp + (rowbase + s) * 1024 + h * 64 + sub * 8);
    ushort8 vvv = *(const ushort8*)(vp + (rowbase + s) * 1024 + h * 64 + sub * 8);
    float kf[8], vf[8];
    float sk = 0.f, sv = 0.f;
#pragma unroll
    for (int j = 0; j < 8; ++j) {
      kf[j] = bf2f(kvv[j]); sk += kf[j] * kf[j];
      vf[j] = bf2f(vvv[j]); sv += vf[j] * vf[j];
    }
    // row = 8 consecutive lanes; reduce across them
    sk += __shfl_xor(sk, 1); sk += __shfl_xor(sk, 2); sk += __shfl_xor(sk, 4);
    sv += __shfl_xor(sv, 1); sv += __shfl_xor(sv, 2); sv += __shfl_xor(sv, 4);
    float ik = 1.f / fmaxf(sqrtf(sk), 1e-12f);
    float iv = 1.f / fmaxf(sqrtf(sv), 1e-12f);
    __syncthreads();
#pragma unroll
    for (int u = 0; u < 8; ++u) {
      ks_[r][sub * 8 + u] = kf[u] * ik;
      vs_[r][sub * 8 + u] = vf[u] * iv;
    }
    __syncthreads();
#pragma unroll 4
    for (int s2 = 0; s2 < 32; ++s2) {
      float4 kf4 = *(const float4*)&ks_[s2][ti * 4];
      float4 vf4 = *(const float4*)&vs_[s2][tj * 4];
      acc[0][0] += kf4.x * vf4.x; acc[0][1] += kf4.x * vf4.y; acc[0][2] += kf4.x * vf4.z; acc[0][3] += kf4.x * vf4.w;
      acc[1][0] += kf4.y * vf4.x; acc[1][1] += kf4.y * vf4.y; acc[1][2] += kf4.y * vf4.z; acc[1][3] += kf4.y * vf4.w;
      acc[2][0] += kf4.z * vf4.x; acc[2][1] += kf4.z * vf4.y; acc[2][2] += kf4.z * vf4.z; acc[2][3] += kf4.z * vf4.w;
      acc[3][0] += kf4.w * vf4.x; acc[3][1] += kf4.w * vf4.y; acc[3][2] += kf4.w * vf4.z; acc[3][3] += kf4.w * vf4.w;
    }
  }
  float* dst = kv + ((size_t)(b * 16 + h)) * 4096;
#pragma unroll
  for (int a = 0; a < 4; ++a)
#pragma unroll
    for (int c = 0; c < 4; ++c)
      atomicAdd(&dst[(ti * 4 + a) * 64 + tj * 4 + c], acc[a][c]);
}

// ---------------- Beff[b][h*64+j][d] = sum_i Wq[h*64+i][d] * kv[b,h,i,j]; beff = bq @ kv ----------------
// grid (dt=8, h=16, b=4), block 256.
__global__ __launch_bounds__(256) void weff_kernel(
    const unsigned short* __restrict__ Wq,  // bf16 [1024][1024]
    const float* __restrict__ bq,           // [1024]
    const float* __restrict__ kv,           // [4][16][64][64] f32
    unsigned short* __restrict__ Beff,      // [4][1024][1024] bf16
    float* __restrict__ beff) {             // [4][1024]
  const int dt = blockIdx.x, h = blockIdx.y, b = blockIdx.z;
  __shared__ float kvS[64 * 64];
  __shared__ float WqF[64 * 128];
  const int tid = threadIdx.x;

  const float* kvsrc = kv + ((size_t)(b * 16 + h)) * 4096;
  for (int e = tid; e < 4096; e += 256) kvS[e] = kvsrc[e];
  {
    int i = tid >> 2, dseg = tid & 3;
    const unsigned short* src = Wq + (size_t)(h * 64 + i) * 1024 + dt * 128 + dseg * 32;
    float* dst = &WqF[i * 128 + dseg * 32];
#pragma unroll
    for (int w = 0; w < 4; ++w) {
      ushort8 vv = ((const ushort8*)src)[w];
#pragma unroll
      for (int u = 0; u < 8; ++u) dst[w * 8 + u] = bf2f(vv[u]);
    }
  }
  __syncthreads();

  const int tj = tid & 63, tg = tid >> 6;
  float o[32];
#pragma unroll
  for (int dd = 0; dd < 32; ++dd) o[dd] = 0.f;
  for (int i = 0; i < 64; ++i) {
    float kvv = kvS[i * 64 + tj];
    const float* wr = &WqF[i * 128 + tg * 32];
#pragma unroll
    for (int dd = 0; dd < 32; ++dd) o[dd] += wr[dd] * kvv;
  }
  unsigned short* dstB = Beff + ((size_t)(b * 1024 + h * 64 + tj)) * 1024 + dt * 128 + tg * 32;
#pragma unroll
  for (int w = 0; w < 4; ++w) {
    ushort8 ov;
#pragma unroll
    for (int u = 0; u < 8; ++u) ov[u] = f2bf(o[w * 8 + u]);
    ((ushort8*)dstB)[w] = ov;
  }
  if (tg == 0 && dt == 0) {
    float s = 0.f;
    for (int i = 0; i < 64; ++i) s += bq[h * 64 + i] * kvS[i * 64 + tj];
    beff[b * 1024 + h * 64 + tj] = s;
  }
}

extern "C" void kernel_launch(void* const* d_in, const int* in_sizes, int n_in,
                              void* d_out, int out_size, void* d_ws, size_t ws_size,
                              hipStream_t stream) {
  const float* q = (const float*)d_in[0];
  const float* k = (const float*)d_in[1];
  const float* v = (const float*)d_in[2];
  const float* Wq = (const float*)d_in[3];
  const float* bq = (const float*)d_in[4];
  const float* Wk = (const float*)d_in[5];
  const float* bk = (const float*)d_in[6];
  const float* Wv = (const float*)d_in[7];
  const float* bv = (const float*)d_in[8];
  float* out = (float*)d_out;

  const size_t NE = (size_t)16384 * 1024;
  const size_t SLOT = NE * 2;  // 32 MB

  char* ws = (char*)d_ws;
  unsigned short* S0 = (unsigned short*)(ws + 0 * SLOT);  // k_bf, later q_bf
  unsigned short* S1 = (unsigned short*)(ws + 1 * SLOT);  // v_bf, later Beff
  unsigned short* S2 = (unsigned short*)(ws + 2 * SLOT);  // kp
  unsigned short* S3 = (unsigned short*)(ws + 3 * SLOT);  // vp
  unsigned short* Wqb = (unsigned short*)(ws + 4 * SLOT);
  unsigned short* Wkb = (unsigned short*)(ws + 4 * SLOT + 2097152);
  unsigned short* Wvb = (unsigned short*)(ws + 4 * SLOT + 2 * 2097152);
  float* kvb = (float*)(ws + 4 * SLOT + 3 * 2097152);                 // 1 MB
  float* beff = (float*)(ws + 4 * SLOT + 3 * 2097152 + 1048576);      // 16 KB
  unsigned short* Beff = S1;                                          // 8 MB inside S1

  // 1) convert k, v and the three weight matrices to bf16
  cvt2_kernel<<<dim3(8192, 2), 256, 0, stream>>>(k, v, S0, S1, (int)(NE / 8));
  cvt3w_kernel<<<dim3(512, 3), 256, 0, stream>>>(Wq, Wk, Wv, Wqb, Wkb, Wvb, 131072);

  // 2) projections kp = k@Wk^T+bk -> S2, vp = v@Wv^T+bv -> S3 (batched, XCD-swizzled)
  proj_gemm_kernel<<<dim3(8, 128, 2), 256, 0, stream>>>(S0, S1, Wkb, Wvb, bk, bv, S2, S3);

  // 3) kv = norm(kh)^T norm(vh) per (b,h), norm fused
  hipMemsetAsync(kvb, 0, 64 * 64 * 64 * sizeof(float), stream);
  kv_kernel<<<dim3(16, 16, 4), 256, 0, stream>>>(S2, S3, kvb);

  // 4) Beff = Wq^T-folded kv (bf16), beff = bq @ kv
  weff_kernel<<<dim3(8, 16, 4), 256, 0, stream>>>(Wqb, bq, kvb, Beff, beff);

  // 5) convert q (reusing S0)
  cvt_kernel<<<8192, 256, 0, stream>>>(q, S0, (int)(NE / 8));

  // 6) out = q_bf @ Beff^T + beff (f32 out, XCD-swizzled)
  final_gemm_kernel<<<dim3(8, 128), 256, 0, stream>>>(S0, Beff, beff, out);
}

// Round 3
// 275.756 us; speedup vs baseline: 1.3460x; 1.0363x over previous
//
#include <hip/hip_runtime.h>
#include <hip/hip_bf16.h>
#include <stdint.h>

typedef __attribute__((ext_vector_type(8))) short bf16x8;
typedef __attribute__((ext_vector_type(4))) float f32x4;
typedef __attribute__((ext_vector_type(8))) unsigned short ushort8;
typedef __attribute__((ext_vector_type(4))) unsigned short ushort4v;

__device__ __forceinline__ float bf2f(unsigned short u) {
  union { unsigned int i; float f; } x; x.i = ((unsigned int)u) << 16; return x.f;
}
__device__ __forceinline__ unsigned short f2bf(float f) {
  union { __hip_bfloat16 h; unsigned short u; } x; x.h = __float2bfloat16(f); return x.u;
}

__device__ __forceinline__ void gload_lds16(const void* g, void* l) {
  __builtin_amdgcn_global_load_lds((__attribute__((address_space(1))) const void*)g,
                                   (__attribute__((address_space(3))) void*)l, 16, 0, 0);
}

// ---------------- f32 -> bf16 convert, 3 tensors batched on z ----------------
__global__ __launch_bounds__(256) void cvt3_kernel(const float* __restrict__ a,
                                                   const float* __restrict__ b,
                                                   const float* __restrict__ c,
                                                   unsigned short* __restrict__ oa,
                                                   unsigned short* __restrict__ ob,
                                                   unsigned short* __restrict__ oc,
                                                   int n8) {
  const float* in = blockIdx.y == 0 ? a : blockIdx.y == 1 ? b : c;
  unsigned short* out = blockIdx.y == 0 ? oa : blockIdx.y == 1 ? ob : oc;
  int i = blockIdx.x * 256 + threadIdx.x;
  if (i >= n8) return;
  const float4* p = (const float4*)(in + (size_t)i * 8);
  float4 x = p[0], y = p[1];
  ushort8 o;
  o[0] = f2bf(x.x); o[1] = f2bf(x.y); o[2] = f2bf(x.z); o[3] = f2bf(x.w);
  o[4] = f2bf(y.x); o[5] = f2bf(y.y); o[6] = f2bf(y.z); o[7] = f2bf(y.w);
  *(ushort8*)(out + (size_t)i * 8) = o;
}

// ---------------- fused proj(k)+norm + proj(v)+norm + kv, one block = 128x128 tile ----------------
// 512 threads = 8 waves (4 row-groups x 2 heads). LDS ~100KB -> 1 block/CU, 2 waves/SIMD.
__global__ __launch_bounds__(512) void projkv_kernel(
    const unsigned short* __restrict__ kbf,
    const unsigned short* __restrict__ vbf,
    const unsigned short* __restrict__ Wkb,
    const unsigned short* __restrict__ Wvb,
    const float* __restrict__ bkb,
    const float* __restrict__ bvb,
    float* __restrict__ kv) {
  __shared__ unsigned short Ab[2][128][32];
  __shared__ unsigned short Bb[2][128][32];
  __shared__ unsigned short khT[128][136];  // [col][row], stride 272B = 17*16B
  __shared__ unsigned short vhT[128][136];

  const int flat = blockIdx.y * 8 + blockIdx.x;  // nwg = 1024, %8 == 0
  const int swz = (flat & 7) * 128 + (flat >> 3);
  const int bm = swz >> 3, bn = swz & 7;
  const int b = bm >> 5;

  const int tid = threadIdx.x;
  const int wid = tid >> 6;
  const int lane = tid & 63;
  const int wrow = (wid >> 1) * 32;   // wave: 32 rows x 64 cols (one head)
  const int wcol = (wid & 1) * 64;
  const int fr = lane & 15, fk = (lane >> 4) * 8;
  const int g4 = (lane >> 4) * 4;

  // staging: wave w covers rows w*16..w*16+15, lane i -> LDS base + i*16
  const size_t abase = (size_t)(bm * 128 + wid * 16 + (lane >> 2)) * 1024 + (lane & 3) * 8;
  const size_t bbase = (size_t)(bn * 128 + wid * 16 + (lane >> 2)) * 1024 + (lane & 3) * 8;

  f32x4 acc[2][4];

#define STAGE_PK(buf, Aptr, Bptr, kt)                         \
  gload_lds16(Aptr + abase + (kt), &Ab[buf][wid * 16][0]);    \
  gload_lds16(Bptr + bbase + (kt), &Bb[buf][wid * 16][0]);

  auto gemm_phase = [&](const unsigned short* __restrict__ A,
                        const unsigned short* __restrict__ B) {
#pragma unroll
    for (int m = 0; m < 2; ++m)
#pragma unroll
      for (int n = 0; n < 4; ++n) acc[m][n] = (f32x4){0.f, 0.f, 0.f, 0.f};
    STAGE_PK(0, A, B, 0);
    __syncthreads();
    for (int t = 0; t < 32; ++t) {
      const int cur = t & 1;
      if (t < 31) { STAGE_PK(cur ^ 1, A, B, (t + 1) * 32); }
      bf16x8 af[2], bfv[4];
#pragma unroll
      for (int m = 0; m < 2; ++m) af[m] = *(const bf16x8*)&Ab[cur][wrow + m * 16 + fr][fk];
#pragma unroll
      for (int n = 0; n < 4; ++n) bfv[n] = *(const bf16x8*)&Bb[cur][wcol + n * 16 + fr][fk];
#pragma unroll
      for (int m = 0; m < 2; ++m)
#pragma unroll
        for (int n = 0; n < 4; ++n)
          acc[m][n] = __builtin_amdgcn_mfma_f32_16x16x32_bf16(af[m], bfv[n], acc[m][n], 0, 0, 0);
      __syncthreads();
    }
  };

  // bias + per-row L2 norm over this wave's 64-col head, write transposed bf16 tile
  auto norm_phase = [&](const float* __restrict__ bias, unsigned short (*T)[136]) {
    float bsv[4];
#pragma unroll
    for (int n = 0; n < 4; ++n) bsv[n] = bias[bn * 128 + wcol + n * 16 + fr];
#pragma unroll
    for (int m = 0; m < 2; ++m) {
      float val[4][4];  // [n][j]
      float inv[4];
#pragma unroll
      for (int j = 0; j < 4; ++j) {
        float s = 0.f;
#pragma unroll
        for (int n = 0; n < 4; ++n) {
          val[n][j] = acc[m][n][j] + bsv[n];
          s += val[n][j] * val[n][j];
        }
        s += __shfl_xor(s, 1); s += __shfl_xor(s, 2);
        s += __shfl_xor(s, 4); s += __shfl_xor(s, 8);
        inv[j] = 1.f / fmaxf(sqrtf(s), 1e-12f);
      }
      const int row0 = wrow + m * 16 + g4;
#pragma unroll
      for (int n = 0; n < 4; ++n) {
        ushort4v pk;
#pragma unroll
        for (int j = 0; j < 4; ++j) pk[j] = f2bf(val[n][j] * inv[j]);
        *(ushort4v*)&T[wcol + n * 16 + fr][row0] = pk;
      }
    }
  };

  gemm_phase(kbf, Wkb);
  norm_phase(bkb, khT);
  gemm_phase(vbf, Wvb);
  norm_phase(bvb, vhT);
  __syncthreads();

  // kv[i][j] += sum_s khT[i][s]*vhT[j][s]; wave w: head = w&1, i-tile = w>>2? no: ib = w>>1
  const int hh = wid & 1;
  const int ib = wid >> 1;  // i-tile 0..3 (16 rows each)
  f32x4 acc2[4];
#pragma unroll
  for (int n = 0; n < 4; ++n) acc2[n] = (f32x4){0.f, 0.f, 0.f, 0.f};
#pragma unroll
  for (int ks = 0; ks < 4; ++ks) {
    bf16x8 a2 = *(const bf16x8*)&khT[hh * 64 + ib * 16 + fr][ks * 32 + fk];
    bf16x8 b2[4];
#pragma unroll
    for (int jt = 0; jt < 4; ++jt)
      b2[jt] = *(const bf16x8*)&vhT[hh * 64 + jt * 16 + fr][ks * 32 + fk];
#pragma unroll
    for (int jt = 0; jt < 4; ++jt)
      acc2[jt] = __builtin_amdgcn_mfma_f32_16x16x32_bf16(a2, b2[jt], acc2[jt], 0, 0, 0);
  }
  float* dst = kv + ((size_t)(b * 16 + bn * 2 + hh)) * 4096;
#pragma unroll
  for (int jt = 0; jt < 4; ++jt)
#pragma unroll
    for (int jj = 0; jj < 4; ++jj) {
      int i = ib * 16 + g4 + jj;
      int j = jt * 16 + fr;
      atomicAdd(&dst[i * 64 + j], acc2[jt][jj]);
    }
#undef STAGE_PK
}

// ---------------- final GEMM: out = q_bf @ Beff_b^T + beff_b (f32 out), dbuf ----------------
__global__ __launch_bounds__(256) void final_gemm_kernel(
    const unsigned short* __restrict__ A,     // q_bf [16384][1024]
    const unsigned short* __restrict__ Beff,  // [4][1024][1024] bf16
    const float* __restrict__ beff,           // [4][1024]
    float* __restrict__ out) {
  __shared__ unsigned short Ab[2][128][32];
  __shared__ unsigned short Bb[2][128][32];
  const int flat = blockIdx.y * 8 + blockIdx.x;  // 1024
  const int swz = (flat & 7) * 128 + (flat >> 3);
  const int bm = swz >> 3, bn = swz & 7;
  const int b = bm >> 5;
  const unsigned short* B = Beff + (size_t)b * 1048576;
  const float* bias = beff + b * 1024;

  const int tid = threadIdx.x, wid = tid >> 6, lane = tid & 63;
  const int wrow = (wid >> 1) * 64, wcol = (wid & 1) * 64;
  const int lrow = lane >> 2, lcol = lane & 3;
  const int fr = lane & 15, fk = (lane >> 4) * 8;

  f32x4 acc[4][4];
#pragma unroll
  for (int m = 0; m < 4; ++m)
#pragma unroll
    for (int n = 0; n < 4; ++n) acc[m][n] = (f32x4){0.f, 0.f, 0.f, 0.f};

  const size_t abase = (size_t)(bm * 128) * 1024;
  const size_t bbase = (size_t)(bn * 128) * 1024;

#define STAGE_FG(buf, kt)                                                          \
  _Pragma("unroll") for (int it = 0; it < 2; ++it) {                               \
    const int chunk = wid * 2 + it;                                                \
    gload_lds16(A + abase + (size_t)(chunk * 16 + lrow) * 1024 + (kt) + lcol * 8,  \
                &Ab[buf][chunk * 16][0]);                                          \
    gload_lds16(B + bbase + (size_t)(chunk * 16 + lrow) * 1024 + (kt) + lcol * 8,  \
                &Bb[buf][chunk * 16][0]);                                          \
  }

  STAGE_FG(0, 0);
  __syncthreads();
  for (int t = 0; t < 32; ++t) {
    const int cur = t & 1;
    if (t < 31) { STAGE_FG(cur ^ 1, (t + 1) * 32); }
    bf16x8 af[4], bfv[4];
#pragma unroll
    for (int m = 0; m < 4; ++m) af[m] = *(const bf16x8*)&Ab[cur][wrow + m * 16 + fr][fk];
#pragma unroll
    for (int n = 0; n < 4; ++n) bfv[n] = *(const bf16x8*)&Bb[cur][wcol + n * 16 + fr][fk];
#pragma unroll
    for (int m = 0; m < 4; ++m)
#pragma unroll
      for (int n = 0; n < 4; ++n)
        acc[m][n] = __builtin_amdgcn_mfma_f32_16x16x32_bf16(af[m], bfv[n], acc[m][n], 0, 0, 0);
    __syncthreads();
  }
#undef STAGE_FG

#pragma unroll
  for (int n = 0; n < 4; ++n) {
    int col = bn * 128 + wcol + n * 16 + fr;
    float bsv = bias[col];
#pragma unroll
    for (int m = 0; m < 4; ++m) {
#pragma unroll
      for (int j = 0; j < 4; ++j) {
        int row = bm * 128 + wrow + m * 16 + (lane >> 4) * 4 + j;
        out[(size_t)row * 1024 + col] = acc[m][n][j] + bsv;
      }
    }
  }
}

// ---------------- Beff[b][h*64+j][d] = sum_i Wq[h*64+i][d] * kv[b,h,i,j]; beff = bq @ kv ----------------
__global__ __launch_bounds__(256) void weff_kernel(
    const unsigned short* __restrict__ Wq,
    const float* __restrict__ bq,
    const float* __restrict__ kv,
    unsigned short* __restrict__ Beff,
    float* __restrict__ beff) {
  const int dt = blockIdx.x, h = blockIdx.y, b = blockIdx.z;
  __shared__ float kvS[64 * 64];
  __shared__ float WqF[64 * 128];
  const int tid = threadIdx.x;

  const float* kvsrc = kv + ((size_t)(b * 16 + h)) * 4096;
  for (int e = tid; e < 4096; e += 256) kvS[e] = kvsrc[e];
  {
    int i = tid >> 2, dseg = tid & 3;
    const unsigned short* src = Wq + (size_t)(h * 64 + i) * 1024 + dt * 128 + dseg * 32;
    float* dst = &WqF[i * 128 + dseg * 32];
#pragma unroll
    for (int w = 0; w < 4; ++w) {
      ushort8 vv = ((const ushort8*)src)[w];
#pragma unroll
      for (int u = 0; u < 8; ++u) dst[w * 8 + u] = bf2f(vv[u]);
    }
  }
  __syncthreads();

  const int tj = tid & 63, tg = tid >> 6;
  float o[32];
#pragma unroll
  for (int dd = 0; dd < 32; ++dd) o[dd] = 0.f;
  for (int i = 0; i < 64; ++i) {
    float kvv = kvS[i * 64 + tj];
    const float* wr = &WqF[i * 128 + tg * 32];
#pragma unroll
    for (int dd = 0; dd < 32; ++dd) o[dd] += wr[dd] * kvv;
  }
  unsigned short* dstB = Beff + ((size_t)(b * 1024 + h * 64 + tj)) * 1024 + dt * 128 + tg * 32;
#pragma unroll
  for (int w = 0; w < 4; ++w) {
    ushort8 ov;
#pragma unroll
    for (int u = 0; u < 8; ++u) ov[u] = f2bf(o[w * 8 + u]);
    ((ushort8*)dstB)[w] = ov;
  }
  if (tg == 0 && dt == 0) {
    float s = 0.f;
    for (int i = 0; i < 64; ++i) s += bq[h * 64 + i] * kvS[i * 64 + tj];
    beff[b * 1024 + h * 64 + tj] = s;
  }
}

extern "C" void kernel_launch(void* const* d_in, const int* in_sizes, int n_in,
                              void* d_out, int out_size, void* d_ws, size_t ws_size,
                              hipStream_t stream) {
  const float* q = (const float*)d_in[0];
  const float* k = (const float*)d_in[1];
  const float* v = (const float*)d_in[2];
  const float* Wq = (const float*)d_in[3];
  const float* bq = (const float*)d_in[4];
  const float* Wk = (const float*)d_in[5];
  const float* bk = (const float*)d_in[6];
  const float* Wv = (const float*)d_in[7];
  const float* bv = (const float*)d_in[8];
  float* out = (float*)d_out;

  const size_t NE = (size_t)16384 * 1024;
  const size_t SLOT = NE * 2;  // 32 MB

  char* ws = (char*)d_ws;
  unsigned short* S0 = (unsigned short*)(ws + 0 * SLOT);  // q_bf
  unsigned short* S1 = (unsigned short*)(ws + 1 * SLOT);  // k_bf, later Beff
  unsigned short* S2 = (unsigned short*)(ws + 2 * SLOT);  // v_bf
  unsigned short* Wqb = (unsigned short*)(ws + 3 * SLOT);
  unsigned short* Wkb = (unsigned short*)(ws + 3 * SLOT + 2097152);
  unsigned short* Wvb = (unsigned short*)(ws + 3 * SLOT + 2 * 2097152);
  float* kvb = (float*)(ws + 3 * SLOT + 3 * 2097152);             // 1 MB
  float* beff = (float*)(ws + 3 * SLOT + 3 * 2097152 + 1048576);  // 16 KB
  unsigned short* Beff = S1;

  // 1) convert q,k,v and weights to bf16
  cvt3_kernel<<<dim3(8192, 3), 256, 0, stream>>>(q, k, v, S0, S1, S2, (int)(NE / 8));
  cvt3_kernel<<<dim3(512, 3), 256, 0, stream>>>(Wq, Wk, Wv, Wqb, Wkb, Wvb, 131072);

  // 2) fused proj + norm + kv
  hipMemsetAsync(kvb, 0, 64 * 64 * 64 * sizeof(float), stream);
  projkv_kernel<<<dim3(8, 128), 512, 0, stream>>>(S1, S2, Wkb, Wvb, bk, bv, kvb);

  // 3) Beff = Wq-folded kv (bf16), beff = bq @ kv  (writes into S1 after k_bf is dead)
  weff_kernel<<<dim3(8, 16, 4), 256, 0, stream>>>(Wqb, bq, kvb, Beff, beff);

  // 4) out = q_bf @ Beff^T + beff (f32 out)
  final_gemm_kernel<<<dim3(8, 128), 256, 0, stream>>>(S0, Beff, beff, out);
}